// Round 7
// baseline (518.186 us; speedup 1.0000x reference)
//
#include <hip/hip_runtime.h>

#define T_N 1024
#define H_N 128
#define CH   128
#define NCH (T_N / CH)   // 8
#define SPAD 136         // staging row stride (shorts) for weight transposes
#define PPAD 132         // pT row stride (floats): 528 B, 16B-aligned, 2-way-free step reads
#define XGRP 1040        // bytes per 2-row DMA group (1024 data + 16 pad)

typedef __attribute__((ext_vector_type(8))) short bf16x8;
typedef __attribute__((ext_vector_type(4))) float f32x4;

// step-loop barrier: LDS-only drain, NO vmcnt (x-DMA stays in flight)
#define BAR_LGKM() asm volatile("s_waitcnt lgkmcnt(0)\n\ts_barrier" ::: "memory")

__device__ __forceinline__ short f2bf_rne(float f) {
    union { float f; unsigned int i; } v; v.f = f;
    unsigned int r = v.i + 0x7FFFu + ((v.i >> 16) & 1u);
    return (short)(r >> 16);
}
__device__ __forceinline__ float tanh_fast(float x) {
    return 1.0f - 2.0f / (__expf(2.0f * x) + 1.0f);
}
// state-slot permutation: col c=[wv:2][u:1][l:4] -> slot [wv:2][l:4][u:1]
__device__ __forceinline__ int slotof(int c) {
    return (c & 0x60) | ((c & 0x0F) << 1) | ((c >> 4) & 1);
}

// One block per batch row; 4 waves; wave wv owns cols {32wv+l, 32wv+16+l}.
__global__ __launch_bounds__(256, 1) void k_fused(const float* __restrict__ x,
                                                  const float* __restrict__ w,
                                                  const float* __restrict__ wst,
                                                  const float* __restrict__ bias,
                                                  float* __restrict__ out) {
    __shared__ __align__(16) float pT[H_N * PPAD];   // 67584 B: proj chunk [h][t]; weight staging at init
    __shared__ __align__(16) char  xbuf[64 * XGRP];  // 66560 B: fp32 x chunk (single buffer, DMA overlapped)
    __shared__ __align__(16) short sst[2][H_N];      // 512 B: slot-permuted bf16 state, double buffered

    const int tid  = threadIdx.x;
    const int wv   = tid >> 6;
    const int lane = tid & 63;
    const int l = lane & 15;
    const int q = lane >> 4;
    const int r = blockIdx.x;
    const float* xrow = x + (size_t)r * T_N * H_N;
    const f32x4 zero4 = (f32x4){0.f, 0.f, 0.f, 0.f};

    // ---- DMA chunk 0 (wave wv: groups 16wv..16wv+15) ----
    {
        const char* gsrc = (const char*)xrow;
        #pragma unroll
        for (int kk = 0; kk < 16; ++kk) {
            int k = wv * 16 + kk;
            __builtin_amdgcn_global_load_lds(
                (const __attribute__((address_space(1))) void*)(gsrc + k * 1024 + lane * 16),
                (__attribute__((address_space(3))) void*)(&xbuf[k * XGRP]),
                16, 0, 0);
        }
    }

    short* stg = reinterpret_cast<short*>(pT);

    // ---- stage wst -> bf16 [n][k_slot] (k-dim slot-permuted to match state layout) ----
    for (int e = tid * 4; e < H_N * H_N; e += 1024) {
        int k = e >> 7, n = e & 127, s = slotof(k);
        float4 a4 = *reinterpret_cast<const float4*>(wst + e);
        stg[(n + 0) * SPAD + s] = f2bf_rne(a4.x);
        stg[(n + 1) * SPAD + s] = f2bf_rne(a4.y);
        stg[(n + 2) * SPAD + s] = f2bf_rne(a4.z);
        stg[(n + 3) * SPAD + s] = f2bf_rne(a4.w);
    }
    __syncthreads();
    bf16x8 wf[2][4];   // state-W B-frags for this wave's nt pair (32 VGPRs)
    #pragma unroll
    for (int b = 0; b < 2; ++b)
        #pragma unroll
        for (int ks = 0; ks < 4; ++ks)
            wf[b][ks] = *reinterpret_cast<const bf16x8*>(
                &stg[(16 * (2 * wv + b) + l) * SPAD + ks * 32 + q * 8]);
    __syncthreads();

    // ---- stage w -> bf16 [n][k] (natural k) ----
    for (int e = tid * 4; e < H_N * H_N; e += 1024) {
        int k = e >> 7, n = e & 127;
        float4 a4 = *reinterpret_cast<const float4*>(w + e);
        stg[(n + 0) * SPAD + k] = f2bf_rne(a4.x);
        stg[(n + 1) * SPAD + k] = f2bf_rne(a4.y);
        stg[(n + 2) * SPAD + k] = f2bf_rne(a4.z);
        stg[(n + 3) * SPAD + k] = f2bf_rne(a4.w);
    }
    __syncthreads();
    bf16x8 wfin[2][4];   // input-proj B-frags (32 VGPRs)
    #pragma unroll
    for (int b = 0; b < 2; ++b)
        #pragma unroll
        for (int ks = 0; ks < 4; ++ks)
            wfin[b][ks] = *reinterpret_cast<const bf16x8*>(
                &stg[(16 * (2 * wv + b) + l) * SPAD + ks * 32 + q * 8]);
    float bv0 = bias[16 * (2 * wv + 0) + l];
    float bv1 = bias[16 * (2 * wv + 1) + l];
    __syncthreads();   // staging reads done; pT free

    int par = 0;
    float y0 = 0.f, y1 = 0.f;

    #pragma unroll 1
    for (int c = 0; c < NCH; ++c) {
        __syncthreads();   // full drain: xbuf DMA complete, prev chunk done with pT

        // ---- chunk GEMM: wave wv -> its 2 n-tiles, all 128 t-rows ----
        #pragma unroll
        for (int rt = 0; rt < 8; ++rt) {
            int row = rt * 16 + l;
            const float* pr = reinterpret_cast<const float*>(
                xbuf + (row >> 1) * XGRP + (row & 1) * 512);
            bf16x8 ax[4];
            #pragma unroll
            for (int ks = 0; ks < 4; ++ks) {
                float4 u0 = *reinterpret_cast<const float4*>(pr + ks * 32 + q * 8);
                float4 u1 = *reinterpret_cast<const float4*>(pr + ks * 32 + q * 8 + 4);
                bf16x8 f;
                f[0] = f2bf_rne(u0.x); f[1] = f2bf_rne(u0.y);
                f[2] = f2bf_rne(u0.z); f[3] = f2bf_rne(u0.w);
                f[4] = f2bf_rne(u1.x); f[5] = f2bf_rne(u1.y);
                f[6] = f2bf_rne(u1.z); f[7] = f2bf_rne(u1.w);
                ax[ks] = f;
            }
            #pragma unroll
            for (int b = 0; b < 2; ++b) {
                f32x4 acc;
                #pragma unroll
                for (int ks = 0; ks < 4; ++ks)
                    acc = __builtin_amdgcn_mfma_f32_16x16x32_bf16(
                        ax[ks], wfin[b][ks], ks == 0 ? zero4 : acc, 0, 0, 0);
                float bb = b ? bv1 : bv0;
                f32x4 o = (f32x4){acc[0] + bb, acc[1] + bb, acc[2] + bb, acc[3] + bb};
                *reinterpret_cast<f32x4*>(
                    &pT[(16 * (2 * wv + b) + l) * PPAD + rt * 16 + q * 4]) = o;
            }
        }
        BAR_LGKM();   // pT ready; all xbuf reads retired (safe to refill)

        // ---- DMA next chunk into xbuf (overlaps the whole step loop) ----
        if (c + 1 < NCH) {
            const char* gsrc = (const char*)(xrow + (size_t)(c + 1) * CH * H_N);
            #pragma unroll
            for (int kk = 0; kk < 16; ++kk) {
                int k = wv * 16 + kk;
                __builtin_amdgcn_global_load_lds(
                    (const __attribute__((address_space(1))) void*)(gsrc + k * 1024 + lane * 16),
                    (__attribute__((address_space(3))) void*)(&xbuf[k * XGRP]),
                    16, 0, 0);
            }
        }

        int tstart = 0;
        if (c == 0) {
            if (tid < 128)   // wave-uniform (waves 0,1)
                sst[0][slotof(tid)] = f2bf_rne(tanh_fast(pT[tid * PPAD]));
            BAR_LGKM();
            tstart = 1;
            par = 0;
        }

        float p0 = pT[(32 * wv + l) * PPAD + tstart];
        float p1 = pT[(32 * wv + 16 + l) * PPAD + tstart];

        // ---- step loop: lgkm-only barrier, depth-1 MFMA, conflict-free packed write ----
        #pragma unroll 1
        for (int t = tstart; t < CH; ++t) {
            bf16x8 a[4];
            #pragma unroll
            for (int ks = 0; ks < 4; ++ks)
                a[ks] = *reinterpret_cast<const bf16x8*>(&sst[par][ks * 32 + q * 8]);

            f32x4 acc[8];
            #pragma unroll
            for (int ks = 0; ks < 4; ++ks) {
                acc[ks]     = __builtin_amdgcn_mfma_f32_16x16x32_bf16(a[ks], wf[0][ks], zero4, 0, 0, 0);
                acc[4 + ks] = __builtin_amdgcn_mfma_f32_16x16x32_bf16(a[ks], wf[1][ks], zero4, 0, 0, 0);
            }

            int tn = (t + 1 < CH) ? t + 1 : t;
            float np0 = pT[(32 * wv + l) * PPAD + tn];
            float np1 = pT[(32 * wv + 16 + l) * PPAD + tn];

            float z0 = p0 + ((acc[0][0] + acc[1][0]) + (acc[2][0] + acc[3][0]));
            float z1 = p1 + ((acc[4][0] + acc[5][0]) + (acc[6][0] + acc[7][0]));
            y0 = tanh_fast(z0);
            y1 = tanh_fast(z1);

            if (q == 0) {   // 16 lanes, 16 distinct banks: conflict-free single b32 write
                unsigned int pk = (unsigned int)(unsigned short)f2bf_rne(y0)
                                | ((unsigned int)(unsigned short)f2bf_rne(y1) << 16);
                *reinterpret_cast<unsigned int*>(&sst[par ^ 1][32 * wv + 2 * l]) = pk;
            }
            p0 = np0; p1 = np1;
            par ^= 1;
            BAR_LGKM();
        }
    }

    if (q == 0) {
        out[r * H_N + 32 * wv + l]      = y0;
        out[r * H_N + 32 * wv + 16 + l] = y1;
    }
}

extern "C" void kernel_launch(void* const* d_in, const int* in_sizes, int n_in,
                              void* d_out, int out_size, void* d_ws, size_t ws_size,
                              hipStream_t stream) {
    const float* x    = (const float*)d_in[0];  // [B][T][D] fp32
    const float* w    = (const float*)d_in[1];  // [D][H]    fp32
    const float* wst  = (const float*)d_in[2];  // [H][H]    fp32
    const float* bias = (const float*)d_in[3];  // [H]       fp32
    float* out = (float*)d_out;                 // [B][H]    fp32

    k_fused<<<256, 256, 0, stream>>>(x, w, wst, bias, out);
}

// Round 8
// 486.059 us; speedup vs baseline: 1.0661x; 1.0661x over previous
//
#include <hip/hip_runtime.h>

#define T_N 1024
#define H_N 128
#define CH   64
#define NCH (T_N / CH)     // 16
#define WPAD 136           // shorts per row of bf16 weight tiles
#define PPAD 68            // floats per row of pT
#define XGRP 1040          // bytes per 2-row DMA group (1024 data + 16 pad)
#define XBUF_BYTES (32 * XGRP)

typedef __attribute__((ext_vector_type(8))) short bf16x8;
typedef __attribute__((ext_vector_type(4))) float f32x4;

// LDS-only barrier: no vmcnt drain, x-DMA stays in flight
#define BAR_LGKM() asm volatile("s_waitcnt lgkmcnt(0)\n\ts_barrier" ::: "memory")

__device__ __forceinline__ short f2bf_rne(float f) {
    union { float f; unsigned int i; } v; v.f = f;
    unsigned int r = v.i + 0x7FFFu + ((v.i >> 16) & 1u);
    return (short)(r >> 16);
}
__device__ __forceinline__ float tanh_fast(float x) {
    return 1.0f - 2.0f / (__expf(2.0f * x) + 1.0f);
}

// One block per batch row; 4 waves split the per-step matvec by column (nt pairs).
__global__ __launch_bounds__(256, 1) void k_fused(const float* __restrict__ x,
                                                  const float* __restrict__ w,
                                                  const float* __restrict__ wst,
                                                  const float* __restrict__ bias,
                                                  float* __restrict__ out) {
    __shared__ __align__(16) short wT[H_N * WPAD];      // input-proj w, bf16 [n][k]
    __shared__ __align__(16) float pT[H_N * PPAD];      // proj chunk [h][t]; wsT staging at startup
    __shared__ __align__(16) char  xbuf[2][XBUF_BYTES]; // fp32 x chunk, DMA double buffer
    __shared__ __align__(16) short sst[2][H_N];         // state double buffer, bf16

    const int tid  = threadIdx.x;
    const int wv   = tid >> 6;       // wave: owns cols 32wv+l, 32wv+16+l (nt = 2wv, 2wv+1)
    const int lane = tid & 63;
    const int l = lane & 15;
    const int q = lane >> 4;
    const int r = blockIdx.x;
    const float* xrow = x + (size_t)r * T_N * H_N;
    const f32x4 zero4 = (f32x4){0.f, 0.f, 0.f, 0.f};

    // ---- DMA chunk 0 (drained by the prologue's first __syncthreads) ----
    {
        const char* gsrc = (const char*)xrow;
        #pragma unroll
        for (int kk = 0; kk < 8; ++kk) {
            int k = wv * 8 + kk;
            __builtin_amdgcn_global_load_lds(
                (const __attribute__((address_space(1))) void*)(gsrc + k * 1024 + lane * 16),
                (__attribute__((address_space(3))) void*)(&xbuf[0][k * XGRP]),
                16, 0, 0);
        }
    }

    // ---- stage wst (bf16 [n][k]) through pT's memory ----
    short* wsT = reinterpret_cast<short*>(pT);
    for (int e = tid * 4; e < H_N * H_N; e += 1024) {
        int k = e >> 7, n = e & 127;
        float4 a4 = *reinterpret_cast<const float4*>(wst + e);
        wsT[(n + 0) * WPAD + k] = f2bf_rne(a4.x);
        wsT[(n + 1) * WPAD + k] = f2bf_rne(a4.y);
        wsT[(n + 2) * WPAD + k] = f2bf_rne(a4.z);
        wsT[(n + 3) * WPAD + k] = f2bf_rne(a4.w);
    }
    __syncthreads();

    bf16x8 wf[2][4];   // state-W B-frags for this wave's nt pair
    #pragma unroll
    for (int b = 0; b < 2; ++b)
        #pragma unroll
        for (int ks = 0; ks < 4; ++ks)
            wf[b][ks] = *reinterpret_cast<const bf16x8*>(
                &wsT[(16 * (2 * wv + b) + l) * WPAD + ks * 32 + q * 8]);
    __syncthreads();

    // ---- input-proj weights -> bf16 [n][k] LDS ----
    for (int e = tid * 4; e < H_N * H_N; e += 1024) {
        int k = e >> 7, n = e & 127;
        float4 a4 = *reinterpret_cast<const float4*>(w + e);
        wT[(n + 0) * WPAD + k] = f2bf_rne(a4.x);
        wT[(n + 1) * WPAD + k] = f2bf_rne(a4.y);
        wT[(n + 2) * WPAD + k] = f2bf_rne(a4.z);
        wT[(n + 3) * WPAD + k] = f2bf_rne(a4.w);
    }

    float bv[8];
    #pragma unroll
    for (int nt = 0; nt < 8; ++nt) bv[nt] = bias[nt * 16 + l];

    int par = 0;
    float y0 = 0.f, y1 = 0.f;
    const int row0 = (32 * wv + l) * PPAD;
    const int row1 = (32 * wv + 16 + l) * PPAD;

    #pragma unroll 1
    for (int c = 0; c < NCH; ++c) {
        // full drain: xbuf[c&1] DMA (issued a whole chunk ago) complete; pT free
        __syncthreads();

        // ---- Δ1: issue DMA for chunk c+1 NOW (writes the other xbuf; overlaps
        //      GEMM + whole step loop; never drained until next chunk top) ----
        if (c + 1 < NCH) {
            const char* gsrc = (const char*)(xrow + (size_t)(c + 1) * CH * H_N);
            char* ldst = &xbuf[(c + 1) & 1][0];
            #pragma unroll
            for (int kk = 0; kk < 8; ++kk) {
                int k = wv * 8 + kk;
                __builtin_amdgcn_global_load_lds(
                    (const __attribute__((address_space(1))) void*)(gsrc + k * 1024 + lane * 16),
                    (__attribute__((address_space(3))) void*)(ldst + k * XGRP),
                    16, 0, 0);
            }
        }

        // ---- chunk GEMM: wave wv computes proj rows [c*64+16wv .. +15] ----
        {
            const char* xb = xbuf[c & 1];
            int row = wv * 16 + l;
            const float* pr = reinterpret_cast<const float*>(
                xb + (row >> 1) * XGRP + (row & 1) * 512);
            bf16x8 ax[4];
            #pragma unroll
            for (int ks = 0; ks < 4; ++ks) {
                float4 u0 = *reinterpret_cast<const float4*>(pr + ks * 32 + q * 8);
                float4 u1 = *reinterpret_cast<const float4*>(pr + ks * 32 + q * 8 + 4);
                bf16x8 f;
                f[0] = f2bf_rne(u0.x); f[1] = f2bf_rne(u0.y);
                f[2] = f2bf_rne(u0.z); f[3] = f2bf_rne(u0.w);
                f[4] = f2bf_rne(u1.x); f[5] = f2bf_rne(u1.y);
                f[6] = f2bf_rne(u1.z); f[7] = f2bf_rne(u1.w);
                ax[ks] = f;
            }
            #pragma unroll
            for (int nt = 0; nt < 8; ++nt) {
                f32x4 acc;
                #pragma unroll
                for (int ks = 0; ks < 4; ++ks) {
                    bf16x8 bw = *reinterpret_cast<const bf16x8*>(
                        &wT[(nt * 16 + l) * WPAD + ks * 32 + q * 8]);
                    acc = __builtin_amdgcn_mfma_f32_16x16x32_bf16(
                        ax[ks], bw, ks == 0 ? zero4 : acc, 0, 0, 0);
                }
                f32x4 o = (f32x4){acc[0] + bv[nt], acc[1] + bv[nt],
                                  acc[2] + bv[nt], acc[3] + bv[nt]};
                *reinterpret_cast<f32x4*>(&pT[(nt * 16 + l) * PPAD + wv * 16 + q * 4]) = o;
            }
        }
        BAR_LGKM();   // Δ1: pT ready — lgkm-only, DMA stays in flight

        if (c == 0) {
            if (tid < 128)
                sst[0][tid] = f2bf_rne(tanh_fast(pT[tid * PPAD + 0]));
            BAR_LGKM();
            par = 0;
        }

        // Δ3: p-block prefetch — one b128 per row covers 4 steps
        float4 pc0 = *reinterpret_cast<const float4*>(&pT[row0]);
        float4 pc1 = *reinterpret_cast<const float4*>(&pT[row1]);

        #pragma unroll 1
        for (int t4 = 0; t4 < CH / 4; ++t4) {
            int t4n = (t4 + 1 < CH / 4) ? t4 + 1 : t4;
            float4 nx0 = *reinterpret_cast<const float4*>(&pT[row0 + t4n * 4]);
            float4 nx1 = *reinterpret_cast<const float4*>(&pT[row1 + t4n * 4]);

            #pragma unroll
            for (int u = 0; u < 4; ++u) {
                if (c == 0 && t4 == 0 && u == 0) continue;   // step 0 handled by init (uniform)

                bf16x8 a[4];
                #pragma unroll
                for (int ks = 0; ks < 4; ++ks)
                    a[ks] = *reinterpret_cast<const bf16x8*>(&sst[par][ks * 32 + q * 8]);

                f32x4 acc[8];
                #pragma unroll
                for (int ks = 0; ks < 4; ++ks) {
                    acc[ks]     = __builtin_amdgcn_mfma_f32_16x16x32_bf16(a[ks], wf[0][ks], zero4, 0, 0, 0);
                    acc[4 + ks] = __builtin_amdgcn_mfma_f32_16x16x32_bf16(a[ks], wf[1][ks], zero4, 0, 0, 0);
                }

                float z0 = pc0[u] + ((acc[0][0] + acc[1][0]) + (acc[2][0] + acc[3][0]));
                float z1 = pc1[u] + ((acc[4][0] + acc[5][0]) + (acc[6][0] + acc[7][0]));
                y0 = tanh_fast(z0);
                y1 = tanh_fast(z1);
                sst[par ^ 1][32 * wv + l]      = f2bf_rne(y0);
                sst[par ^ 1][32 * wv + 16 + l] = f2bf_rne(y1);
                par ^= 1;
                BAR_LGKM();   // Δ2: lgkm-only step barrier
            }
            pc0 = nx0; pc1 = nx1;
        }
    }

    if (q == 0) {
        out[r * H_N + 32 * wv + l]      = y0;
        out[r * H_N + 32 * wv + 16 + l] = y1;
    }
}

extern "C" void kernel_launch(void* const* d_in, const int* in_sizes, int n_in,
                              void* d_out, int out_size, void* d_ws, size_t ws_size,
                              hipStream_t stream) {
    const float* x    = (const float*)d_in[0];  // [B][T][D] fp32
    const float* w    = (const float*)d_in[1];  // [D][H]    fp32
    const float* wst  = (const float*)d_in[2];  // [H][H]    fp32
    const float* bias = (const float*)d_in[3];  // [H]       fp32
    float* out = (float*)d_out;                 // [B][H]    fp32

    k_fused<<<256, 256, 0, stream>>>(x, w, wst, bias, out);
}